// Round 7
// baseline (133.991 us; speedup 1.0000x reference)
//
#include <hip/hip_runtime.h>
#include <hip/hip_bf16.h>

#define T 8192
#define D 128
#define NSPLIT 8
#define JLEN (T / NSPLIT)   /* 1024 */
#define BN 64
#define NITER (JLEN / BN)   /* 16 */
#define BM 128              /* rows per workgroup */
#define LOG2E 1.44269504088896f

typedef _Float16 half2_t __attribute__((ext_vector_type(2)));
typedef _Float16 half4_t __attribute__((ext_vector_type(4)));
typedef _Float16 half8_t __attribute__((ext_vector_type(8)));
typedef __fp16 fp16x2_t __attribute__((ext_vector_type(2)));
typedef float floatx4 __attribute__((ext_vector_type(4)));
typedef float floatx16 __attribute__((ext_vector_type(16)));

// ---------------------------------------------------------------------------
// prep: q16 = f16(question), qT16 = transpose, cm16 = f16(ctx*w_m*log2e),
// qq2[j] = (question[j].w_q)*log2e.  Also zeroes h (atomic target for tail).
// grid 256 (32 rows/block), block 256
// ---------------------------------------------------------------------------
__global__ void prep_kernel(const float* __restrict__ x, const float* __restrict__ kern,
                            _Float16* __restrict__ q16, _Float16* __restrict__ qT16,
                            _Float16* __restrict__ cm16, float* __restrict__ qq2,
                            float* __restrict__ h) {
    const float* context  = x;
    const float* question = x + (size_t)T * D;
    const float* wq = kern + D;
    const float* wm = kern + 2 * D;
    __shared__ __align__(16) _Float16 tile[32][136];
    int j0 = blockIdx.x * 32;
    int t = threadIdx.x;
    if (blockIdx.x == 0 && t < 128) h[t] = 0.f;   // zero atomic accumulator
    int c4 = t & 31;       // float4 index within row (0..31)
    int rsub = t >> 5;     // 0..7
    float4 wqv = ((const float4*)wq)[c4];
    float4 wmv = ((const float4*)wm)[c4];
    for (int p = 0; p < 4; ++p) {
        int row = p * 8 + rsub;
        float4 q = ((const float4*)(question + (size_t)(j0 + row) * D))[c4];
        float4 c = ((const float4*)(context  + (size_t)(j0 + row) * D))[c4];
        half4_t qh;
        qh[0] = (_Float16)q.x; qh[1] = (_Float16)q.y; qh[2] = (_Float16)q.z; qh[3] = (_Float16)q.w;
        *(half4_t*)(q16 + (size_t)(j0 + row) * D + c4 * 4) = qh;
        *(half4_t*)&tile[row][c4 * 4] = qh;
        half4_t ch;
        ch[0] = (_Float16)(c.x * wmv.x * LOG2E); ch[1] = (_Float16)(c.y * wmv.y * LOG2E);
        ch[2] = (_Float16)(c.z * wmv.z * LOG2E); ch[3] = (_Float16)(c.w * wmv.w * LOG2E);
        *(half4_t*)(cm16 + (size_t)(j0 + row) * D + c4 * 4) = ch;
        float s = q.x * wqv.x + q.y * wqv.y + q.z * wqv.z + q.w * wqv.w;
        for (int dx = 1; dx <= 16; dx <<= 1) s += __shfl_xor(s, dx);
        if (c4 == 0) qq2[j0 + row] = s * LOG2E;
    }
    __syncthreads();
    for (int p = 0; p < 2; ++p) {
        int chunk = t + p * 256;
        int d = chunk >> 2, jo = (chunk & 3) * 8;
        half8_t v;
        for (int s2 = 0; s2 < 8; ++s2) v[s2] = tile[jo + s2][d];
        *(half8_t*)(qT16 + (size_t)d * T + j0 + jo) = v;
    }
}

// ---------------------------------------------------------------------------
// flash — EXACT round-2 build (best measured: 57.4us, MfmaUtil 25%).
// 32x32x16 full-rate MFMA both GEMMs; sigma bits2<->3 trick (St C-regs ==
// PV B-frags, zero shuffles); Kt stride-136 / Vt stride-72 rotated layouts
// (~2-way conflicts); reg staging 2 tiles ahead; exact defer-max; fp8 e4m3
// normalized partial output.  2 blocks/CU (LDS 70KB), 176/256 regs used.
// Cross-round law: MFMA-busy is ~14.4us in every healthy build; the wall is
// the per-wave serial path.  Occupancy moves (R4/R5/R6) and score pipelining
// (R3) all regressed or tied -- do not revisit without new counter evidence.
// grid 512 = 64 row-blocks x 8 j-splits, block 256 (4 waves, 32 rows/wave)
// ---------------------------------------------------------------------------
__global__ __launch_bounds__(256, 2)
void flash_kernel(const _Float16* __restrict__ q16, const _Float16* __restrict__ qT16,
                  const _Float16* __restrict__ cm16, const float* __restrict__ qq2,
                  unsigned char* __restrict__ Opart, float* __restrict__ mpart,
                  float* __restrict__ lpart) {
    __shared__ __align__(16) _Float16 Kt[2][64][136];  // [key][d], stride 272B
    __shared__ __align__(16) _Float16 Vt[2][128][72];  // [d][rotated key granule]
    __shared__ __align__(16) float qqs[JLEN];          // biases for this split (4KB)

    const int bx = blockIdx.x;
    const int rb = bx >> 3;
    const int sp = bx & 7;
    const int tid = threadIdx.x;
    const int wave = tid >> 6;
    const int lane = tid & 63;
    const int l31 = lane & 31;
    const int h = lane >> 5;
    const int rbase = rb * BM + wave * 32;
    const int q = rbase + l31;                  // this lane's query row
    // sigma: swap bits 2<->3 (involution). Makes St C-regs == PV B-frags.
    const int sig = (l31 & 19) | ((l31 & 4) << 1) | ((l31 & 8) >> 1);

    ((float4*)qqs)[tid] = ((const float4*)(qq2 + (size_t)sp * JLEN))[tid];

    // B-operand of St: lane holds cm16[q][ks*16 + h*8 + 0..7]
    half8_t qfrag[8];
#pragma unroll
    for (int ks = 0; ks < 8; ++ks)
        qfrag[ks] = *(const half8_t*)(cm16 + (size_t)q * D + ks * 16 + h * 8);

    floatx16 acc[4];   // acc[nt]: O^T tile, row = d-within-tile, col = query
#pragma unroll
    for (int nt = 0; nt < 4; ++nt)
#pragma unroll
        for (int r = 0; r < 16; ++r) acc[nt][r] = 0.f;
    float m_run = -INFINITY, l_run = 0.f;

    const int j0 = sp * JLEN;
    half8_t kreg[4], vreg[4];
    // load tile 0 into regs, commit to buf0, prefetch tile 1
#pragma unroll
    for (int k = 0; k < 4; ++k) {
        int idx = tid + k * 256;
        kreg[k] = *(const half8_t*)(q16 + (size_t)(j0 + (idx >> 4)) * D + (idx & 15) * 8);
        vreg[k] = *(const half8_t*)(qT16 + (size_t)(idx >> 3) * T + j0 + (idx & 7) * 8);
    }
#pragma unroll
    for (int k = 0; k < 4; ++k) {
        int idx = tid + k * 256;
        *(half8_t*)&Kt[0][idx >> 4][(idx & 15) * 8] = kreg[k];
        int dr = idx >> 3, c8 = idx & 7;
        *(half8_t*)&Vt[0][dr][((c8 + (dr & 7)) & 7) * 8] = vreg[k];
    }
#pragma unroll
    for (int k = 0; k < 4; ++k) {
        int idx = tid + k * 256;
        kreg[k] = *(const half8_t*)(q16 + (size_t)(j0 + BN + (idx >> 4)) * D + (idx & 15) * 8);
        vreg[k] = *(const half8_t*)(qT16 + (size_t)(idx >> 3) * T + j0 + BN + (idx & 7) * 8);
    }
    __syncthreads();

    for (int it = 0; it < NITER; ++it) {
        const int cur = it & 1;
        // ---- commit tile it+1 into the other buffer ----
        if (it + 1 < NITER) {
#pragma unroll
            for (int k = 0; k < 4; ++k) {
                int idx = tid + k * 256;
                *(half8_t*)&Kt[cur ^ 1][idx >> 4][(idx & 15) * 8] = kreg[k];
                int dr = idx >> 3, c8 = idx & 7;
                *(half8_t*)&Vt[cur ^ 1][dr][((c8 + (dr & 7)) & 7) * 8] = vreg[k];
            }
        }
        // ---- issue tile it+2 global loads (latency overlaps compute) ----
        if (it + 2 < NITER) {
            int jn = j0 + (it + 2) * BN;
#pragma unroll
            for (int k = 0; k < 4; ++k) {
                int idx = tid + k * 256;
                kreg[k] = *(const half8_t*)(q16 + (size_t)(jn + (idx >> 4)) * D + (idx & 15) * 8);
                vreg[k] = *(const half8_t*)(qT16 + (size_t)(idx >> 3) * T + jn + (idx & 7) * 8);
            }
        }

        // ---- St = K Qm^T + bias (C-init); keys via sigma: key(reg r) =
        //      (r&3) + 4*((r>>2)&1) + 8h + 16*(r>>3)
        floatx16 St[2];
#pragma unroll
        for (int jt = 0; jt < 2; ++jt) {
            const float* qb = &qqs[it * 64 + jt * 32];
            float4 b0 = *(const float4*)(qb + 8 * h);
            float4 b1 = *(const float4*)(qb + 4 + 8 * h);
            float4 b2 = *(const float4*)(qb + 16 + 8 * h);
            float4 b3 = *(const float4*)(qb + 20 + 8 * h);
            St[jt][0]  = b0.x; St[jt][1]  = b0.y; St[jt][2]  = b0.z; St[jt][3]  = b0.w;
            St[jt][4]  = b1.x; St[jt][5]  = b1.y; St[jt][6]  = b1.z; St[jt][7]  = b1.w;
            St[jt][8]  = b2.x; St[jt][9]  = b2.y; St[jt][10] = b2.z; St[jt][11] = b2.w;
            St[jt][12] = b3.x; St[jt][13] = b3.y; St[jt][14] = b3.z; St[jt][15] = b3.w;
            __builtin_amdgcn_s_setprio(1);
#pragma unroll
            for (int ks = 0; ks < 8; ++ks) {
                half8_t a = *(const half8_t*)&Kt[cur][jt * 32 + sig][ks * 16 + h * 8];
                St[jt] = __builtin_amdgcn_mfma_f32_32x32x16_f16(a, qfrag[ks], St[jt], 0, 0, 0);
            }
            __builtin_amdgcn_s_setprio(0);
        }

        // ---- online softmax (exact defer-max) ----
        float mx = St[0][0];
#pragma unroll
        for (int r = 1; r < 16; ++r) mx = fmaxf(mx, St[0][r]);
#pragma unroll
        for (int r = 0; r < 16; ++r) mx = fmaxf(mx, St[1][r]);
        mx = fmaxf(mx, __shfl_xor(mx, 32));
        if (__any(mx > m_run)) {
            float mnew = fmaxf(m_run, mx);
            float alpha = __builtin_amdgcn_exp2f(m_run - mnew);
#pragma unroll
            for (int nt = 0; nt < 4; ++nt)
#pragma unroll
                for (int r = 0; r < 16; ++r) acc[nt][r] *= alpha;
            l_run *= alpha;
            m_run = mnew;
        }
        half2_t pp[2][8];
        float ps = 0.f;
#pragma unroll
        for (int jt = 0; jt < 2; ++jt)
#pragma unroll
            for (int r2 = 0; r2 < 8; ++r2) {
                float p0 = __builtin_amdgcn_exp2f(St[jt][2 * r2]     - m_run);
                float p1 = __builtin_amdgcn_exp2f(St[jt][2 * r2 + 1] - m_run);
                ps += p0 + p1;
                fp16x2_t pk = __builtin_amdgcn_cvt_pkrtz(p0, p1);
                pp[jt][r2] = __builtin_bit_cast(half2_t, pk);
            }
        ps += __shfl_xor(ps, 32);
        l_run += ps;

        // ---- O^T += V^T P from Vt[cur]; B-frag = packed St regs (sigma) ----
        __builtin_amdgcn_s_setprio(1);
#pragma unroll
        for (int jt = 0; jt < 2; ++jt)
#pragma unroll
            for (int kb = 0; kb < 2; ++kb) {
                half8_t pb;
                pb[0] = pp[jt][kb * 4 + 0][0]; pb[1] = pp[jt][kb * 4 + 0][1];
                pb[2] = pp[jt][kb * 4 + 1][0]; pb[3] = pp[jt][kb * 4 + 1][1];
                pb[4] = pp[jt][kb * 4 + 2][0]; pb[5] = pp[jt][kb * 4 + 2][1];
                pb[6] = pp[jt][kb * 4 + 3][0]; pb[7] = pp[jt][kb * 4 + 3][1];
                const int pg = ((jt * 4 + kb * 2 + h) + (l31 & 7)) & 7;
#pragma unroll
                for (int nt = 0; nt < 4; ++nt) {
                    half8_t va = *(const half8_t*)&Vt[cur][nt * 32 + l31][pg * 8];
                    acc[nt] = __builtin_amdgcn_mfma_f32_32x32x16_f16(va, pb, acc[nt], 0, 0, 0);
                }
            }
        __builtin_amdgcn_s_setprio(0);
        __syncthreads();
    }

    // ---- finalize: normalized O (O/l) as fp8 e4m3, 4B packed stores; m,l ----
    if (h == 0) {
        mpart[(size_t)sp * T + q] = m_run;
        lpart[(size_t)sp * T + q] = l_run;
    }
    float rinv = 1.0f / l_run;
#pragma unroll
    for (int nt = 0; nt < 4; ++nt)
#pragma unroll
        for (int rg = 0; rg < 4; ++rg) {
            float v0 = acc[nt][rg * 4 + 0] * rinv;
            float v1 = acc[nt][rg * 4 + 1] * rinv;
            float v2 = acc[nt][rg * 4 + 2] * rinv;
            float v3 = acc[nt][rg * 4 + 3] * rinv;
            unsigned u = (unsigned)__builtin_amdgcn_cvt_pk_fp8_f32(v0, v1, 0, false);
            u = (unsigned)__builtin_amdgcn_cvt_pk_fp8_f32(v2, v3, u, true);
            *(unsigned*)(Opart + ((size_t)sp * T + q) * D + nt * 32 + rg * 8 + 4 * h) = u;
        }
}

// ---------------------------------------------------------------------------
// tail (uniform, no straggler phase): 512 blocks.  Each block merges the 8
// fp8 split partials for its 16 rows -> U_A, AND accumulates its rows'
// h-contribution (ctx[i]*linv[i]) via shfl-reduce + LDS + 128 atomics/block.
// Replaces the old 64-block combine straggler that serialized after merge.
// grid 512, block 256
// ---------------------------------------------------------------------------
__global__ void tail_kernel(const unsigned char* __restrict__ Opart, const float* __restrict__ mpart,
                            const float* __restrict__ lpart, const float* __restrict__ x,
                            float* __restrict__ U_A, float* __restrict__ h) {
    __shared__ float wsum[4][128];
    int t = threadIdx.x;
    int i = blockIdx.x * 16 + (t >> 4);
    int c = t & 15;
    float mp[NSPLIT];
    float mstar = -INFINITY;
    for (int sp = 0; sp < NSPLIT; ++sp) {
        mp[sp] = mpart[(size_t)sp * T + i];
        mstar = fmaxf(mstar, mp[sp]);
    }
    float L = 0.f;
    float u[8];
    for (int k = 0; k < 8; ++k) u[k] = 0.f;
    int d0 = c * 8;
    for (int sp = 0; sp < NSPLIT; ++sp) {
        float w = __builtin_amdgcn_exp2f(mp[sp] - mstar) * lpart[(size_t)sp * T + i];
        L += w;
        uint2 ow = *(const uint2*)(Opart + ((size_t)sp * T + i) * D + d0);
        u[0] += __builtin_amdgcn_cvt_f32_fp8(ow.x, 0) * w;
        u[1] += __builtin_amdgcn_cvt_f32_fp8(ow.x, 1) * w;
        u[2] += __builtin_amdgcn_cvt_f32_fp8(ow.x, 2) * w;
        u[3] += __builtin_amdgcn_cvt_f32_fp8(ow.x, 3) * w;
        u[4] += __builtin_amdgcn_cvt_f32_fp8(ow.y, 0) * w;
        u[5] += __builtin_amdgcn_cvt_f32_fp8(ow.y, 1) * w;
        u[6] += __builtin_amdgcn_cvt_f32_fp8(ow.y, 2) * w;
        u[7] += __builtin_amdgcn_cvt_f32_fp8(ow.y, 3) * w;
    }
    float invL = 1.0f / L;
    float4 s0 = make_float4(u[0] * invL, u[1] * invL, u[2] * invL, u[3] * invL);
    float4 s1 = make_float4(u[4] * invL, u[5] * invL, u[6] * invL, u[7] * invL);
    *(float4*)(U_A + (size_t)i * D + d0) = s0;
    *(float4*)(U_A + (size_t)i * D + d0 + 4) = s1;

    // ---- h contribution: sum over this block's 16 rows of ctx[i][d]*invL ----
    float4 ca = *(const float4*)(x + (size_t)i * D + d0);
    float4 cb = *(const float4*)(x + (size_t)i * D + d0 + 4);
    float hv[8] = { ca.x * invL, ca.y * invL, ca.z * invL, ca.w * invL,
                    cb.x * invL, cb.y * invL, cb.z * invL, cb.w * invL };
    // lanes {c, c+16, c+32, c+48} of each wave hold 4 different rows, same d
#pragma unroll
    for (int k = 0; k < 8; ++k) {
        hv[k] += __shfl_xor(hv[k], 16);
        hv[k] += __shfl_xor(hv[k], 32);
    }
    int lane = t & 63, wv = t >> 6;
    if (lane < 16) {
#pragma unroll
        for (int k = 0; k < 8; ++k) wsum[wv][lane * 8 + k] = hv[k];
    }
    __syncthreads();
    if (t < 128)
        atomicAdd(&h[t], (wsum[0][t] + wsum[1][t]) + (wsum[2][t] + wsum[3][t]));
}

// ---------------------------------------------------------------------------
// assemble G = [ctx, U_A, ctx*U_A, ctx*h]   grid 4096, block 256, float4/thread
// ---------------------------------------------------------------------------
__global__ void assemble_kernel(const float* __restrict__ x, const float* __restrict__ U_A,
                                const float* __restrict__ h, float* __restrict__ out) {
    const float* context = x;
    int gid = blockIdx.x * 256 + threadIdx.x;
    int base = gid * 4;
    int i = base >> 9;
    int c = base & 511;
    int seg = c >> 7, d = c & 127;
    float4 r;
    if (seg == 0) {
        r = *(const float4*)(context + (size_t)i * D + d);
    } else if (seg == 1) {
        r = *(const float4*)(U_A + (size_t)i * D + d);
    } else if (seg == 2) {
        float4 a = *(const float4*)(context + (size_t)i * D + d);
        float4 b = *(const float4*)(U_A + (size_t)i * D + d);
        r = make_float4(a.x * b.x, a.y * b.y, a.z * b.z, a.w * b.w);
    } else {
        float4 a = *(const float4*)(context + (size_t)i * D + d);
        float4 b = *(const float4*)(h + d);
        r = make_float4(a.x * b.x, a.y * b.y, a.z * b.z, a.w * b.w);
    }
    *(float4*)(out + base) = r;
}

// ---------------------------------------------------------------------------
extern "C" void kernel_launch(void* const* d_in, const int* in_sizes, int n_in,
                              void* d_out, int out_size, void* d_ws, size_t ws_size,
                              hipStream_t stream) {
    const float* x = (const float*)d_in[0];
    const float* kern = (const float*)d_in[1];
    float* out = (float*)d_out;

    char* w = (char*)d_ws;
    size_t off = 0;
    _Float16* q16  = (_Float16*)(w + off); off += (size_t)T * D * 2;   // 2 MB
    _Float16* qT16 = (_Float16*)(w + off); off += (size_t)T * D * 2;   // 2 MB
    _Float16* cm16 = (_Float16*)(w + off); off += (size_t)T * D * 2;   // 2 MB
    float* qq2   = (float*)(w + off); off += (size_t)T * 4;            // 32 KB
    float* mpart = (float*)(w + off); off += (size_t)NSPLIT * T * 4;   // 256 KB
    float* lpart = (float*)(w + off); off += (size_t)NSPLIT * T * 4;   // 256 KB
    float* U_A   = (float*)(w + off); off += (size_t)T * D * 4;        // 4 MB
    float* h     = (float*)(w + off); off += (size_t)D * 4;

    // d_out doubles as fp8 split-partial scratch: 8 * T * D * 1B = 8 MB <= 16 MB
    unsigned char* Opart = (unsigned char*)d_out;

    prep_kernel<<<256, 256, 0, stream>>>(x, kern, q16, qT16, cm16, qq2, h);
    flash_kernel<<<512, 256, 0, stream>>>(q16, qT16, cm16, qq2, Opart, mpart, lpart);
    tail_kernel<<<512, 256, 0, stream>>>(Opart, mpart, lpart, x, U_A, h);
    assemble_kernel<<<4096, 256, 0, stream>>>(x, U_A, h, out);
}

// Round 8
// 128.382 us; speedup vs baseline: 1.0437x; 1.0437x over previous
//
#include <hip/hip_runtime.h>
#include <hip/hip_bf16.h>

#define T 8192
#define D 128
#define NSPLIT 8
#define JLEN (T / NSPLIT)   /* 1024 */
#define BN 64
#define NITER (JLEN / BN)   /* 16 */
#define BM 128              /* rows per workgroup */
#define LOG2E 1.44269504088896f

typedef _Float16 half2_t __attribute__((ext_vector_type(2)));
typedef _Float16 half4_t __attribute__((ext_vector_type(4)));
typedef _Float16 half8_t __attribute__((ext_vector_type(8)));
typedef __fp16 fp16x2_t __attribute__((ext_vector_type(2)));
typedef float floatx4 __attribute__((ext_vector_type(4)));
typedef float floatx16 __attribute__((ext_vector_type(16)));

// ---------------------------------------------------------------------------
// prep: q16 = f16(question), qT16 = transpose, cm16 = f16(ctx*w_m*log2e),
// qq2[j] = (question[j].w_q)*log2e.  grid 256, block 256  (R2 verbatim)
// ---------------------------------------------------------------------------
__global__ void prep_kernel(const float* __restrict__ x, const float* __restrict__ kern,
                            _Float16* __restrict__ q16, _Float16* __restrict__ qT16,
                            _Float16* __restrict__ cm16, float* __restrict__ qq2) {
    const float* context  = x;
    const float* question = x + (size_t)T * D;
    const float* wq = kern + D;
    const float* wm = kern + 2 * D;
    __shared__ __align__(16) _Float16 tile[32][136];
    int j0 = blockIdx.x * 32;
    int t = threadIdx.x;
    int c4 = t & 31;
    int rsub = t >> 5;
    float4 wqv = ((const float4*)wq)[c4];
    float4 wmv = ((const float4*)wm)[c4];
    for (int p = 0; p < 4; ++p) {
        int row = p * 8 + rsub;
        float4 q = ((const float4*)(question + (size_t)(j0 + row) * D))[c4];
        float4 c = ((const float4*)(context  + (size_t)(j0 + row) * D))[c4];
        half4_t qh;
        qh[0] = (_Float16)q.x; qh[1] = (_Float16)q.y; qh[2] = (_Float16)q.z; qh[3] = (_Float16)q.w;
        *(half4_t*)(q16 + (size_t)(j0 + row) * D + c4 * 4) = qh;
        *(half4_t*)&tile[row][c4 * 4] = qh;
        half4_t ch;
        ch[0] = (_Float16)(c.x * wmv.x * LOG2E); ch[1] = (_Float16)(c.y * wmv.y * LOG2E);
        ch[2] = (_Float16)(c.z * wmv.z * LOG2E); ch[3] = (_Float16)(c.w * wmv.w * LOG2E);
        *(half4_t*)(cm16 + (size_t)(j0 + row) * D + c4 * 4) = ch;
        float s = q.x * wqv.x + q.y * wqv.y + q.z * wqv.z + q.w * wqv.w;
        for (int dx = 1; dx <= 16; dx <<= 1) s += __shfl_xor(s, dx);
        if (c4 == 0) qq2[j0 + row] = s * LOG2E;
    }
    __syncthreads();
    for (int p = 0; p < 2; ++p) {
        int chunk = t + p * 256;
        int d = chunk >> 2, jo = (chunk & 3) * 8;
        half8_t v;
        for (int s2 = 0; s2 < 8; ++s2) v[s2] = tile[jo + s2][d];
        *(half8_t*)(qT16 + (size_t)d * T + j0 + jo) = v;
    }
}

// ---------------------------------------------------------------------------
// flash — R7 base (55us) + PV-in-St-shadow pipeline + fp8 V.
//  - dependency-stall theory: per-iter wall 8250cyc vs ~5000 pipe work; the
//    serial chain [St 8-deep MFMA latency -> serial softmax -> PV] is the gap.
//  - body order: St(it) -> PV(it-1) [16 indep MFMAs fill St's latency shadow;
//    softmax(it)->PV(it) dep hidden behind St(it+1)] -> softmax(it)->pp.
//    Carried state = packed fp8 P only (8 regs; R3 carried 64 -> spilled).
//  - V triple-buffered in fp8 e4m3 (3 x 9KB; slot (it+1)%3 written, (it-1)%3
//    read -> distinct; one barrier/iter preserved).  PV via
//    mfma_f32_32x32x16_fp8_fp8 (f16-rate); b64 V reads halve LDS bank-passes.
//  - P in (0,1] exact-max: fp8 loses only mass < 2^-9 of max key (negligible);
//    K.Q stays f16; exp/l/rescale stay f32.  acc scale: PV(it-1) lands in
//    m(it-1) scale BEFORE softmax(it) rescales -- exact.
//  - LDS 65KB: Kt[2][64][136] f16 + Vt8[3][128*72] + qqs -> 2 blocks/CU.
// grid 512 = 64 row-blocks x 8 j-splits, block 256 (4 waves, 32 rows/wave)
// Tripwires: WRITE_SIZE >> 9MB = spills; absmax jump = fp8 PV accuracy.
// ---------------------------------------------------------------------------
__global__ __launch_bounds__(256, 2)
void flash_kernel(const _Float16* __restrict__ q16, const _Float16* __restrict__ qT16,
                  const _Float16* __restrict__ cm16, const float* __restrict__ qq2,
                  unsigned char* __restrict__ Opart, float* __restrict__ mpart,
                  float* __restrict__ lpart) {
    __shared__ __align__(16) _Float16 Kt[2][64][136];      // 34.8KB
    __shared__ __align__(16) unsigned char Vt8[3][128 * 72]; // 27.6KB fp8
    __shared__ __align__(16) float qqs[JLEN];              // 4KB

    const int bx = blockIdx.x;
    const int rb = bx >> 3;
    const int sp = bx & 7;
    const int tid = threadIdx.x;
    const int lane = tid & 63;
    const int wave = tid >> 6;
    const int l31 = lane & 31;
    const int h = lane >> 5;
    const int rbase = rb * BM + wave * 32;
    const int q = rbase + l31;
    // sigma: swap bits 2<->3 (involution). Makes St C-regs == PV B-frags.
    const int sig = (l31 & 19) | ((l31 & 4) << 1) | ((l31 & 8) >> 1);

    ((float4*)qqs)[tid] = ((const float4*)(qq2 + (size_t)sp * JLEN))[tid];

    half8_t qfrag[8];
#pragma unroll
    for (int ks = 0; ks < 8; ++ks)
        qfrag[ks] = *(const half8_t*)(cm16 + (size_t)q * D + ks * 16 + h * 8);

    floatx16 acc[4];
#pragma unroll
    for (int nt = 0; nt < 4; ++nt)
#pragma unroll
        for (int r = 0; r < 16; ++r) acc[nt][r] = 0.f;
    float m_run = -INFINITY, l_run = 0.f;

    const int j0 = sp * JLEN;
    half8_t kreg[4], vreg[4];
    long ppE[4], ppO[4];
#pragma unroll
    for (int k = 0; k < 4; ++k) { ppE[k] = 0; ppO[k] = 0; }

    // ---- prologue: tile 0 -> LDS (K f16, V fp8), tile 1 -> regs ----
#pragma unroll
    for (int k = 0; k < 4; ++k) {
        int idx = tid + k * 256;
        kreg[k] = *(const half8_t*)(q16 + (size_t)(j0 + (idx >> 4)) * D + (idx & 15) * 8);
        vreg[k] = *(const half8_t*)(qT16 + (size_t)(idx >> 3) * T + j0 + (idx & 7) * 8);
    }
#pragma unroll
    for (int k = 0; k < 4; ++k) {
        int idx = tid + k * 256;
        *(half8_t*)&Kt[0][idx >> 4][(idx & 15) * 8] = kreg[k];
        int drr = idx >> 3, g = idx & 7;
        unsigned u0 = (unsigned)__builtin_amdgcn_cvt_pk_fp8_f32((float)vreg[k][0], (float)vreg[k][1], 0, false);
        u0 = (unsigned)__builtin_amdgcn_cvt_pk_fp8_f32((float)vreg[k][2], (float)vreg[k][3], u0, true);
        unsigned u1 = (unsigned)__builtin_amdgcn_cvt_pk_fp8_f32((float)vreg[k][4], (float)vreg[k][5], 0, false);
        u1 = (unsigned)__builtin_amdgcn_cvt_pk_fp8_f32((float)vreg[k][6], (float)vreg[k][7], u1, true);
        *(uint2*)&Vt8[0][drr * 72 + ((g + (drr & 7)) & 7) * 8] = make_uint2(u0, u1);
    }
#pragma unroll
    for (int k = 0; k < 4; ++k) {
        int idx = tid + k * 256;
        kreg[k] = *(const half8_t*)(q16 + (size_t)(j0 + BN + (idx >> 4)) * D + (idx & 15) * 8);
        vreg[k] = *(const half8_t*)(qT16 + (size_t)(idx >> 3) * T + j0 + BN + (idx & 7) * 8);
    }
    __syncthreads();

#define FBODY(IT, PPW, PPR)                                                          \
    do {                                                                             \
        const int cur = (IT) & 1;                                                    \
        const int vsw = ((IT) + 1) % 3;                                              \
        const int vsr = ((IT) + 2) % 3;                                              \
        if ((IT) + 1 < NITER) {                                                      \
            _Pragma("unroll")                                                        \
            for (int k = 0; k < 4; ++k) {                                            \
                int idx = tid + k * 256;                                             \
                *(half8_t*)&Kt[cur ^ 1][idx >> 4][(idx & 15) * 8] = kreg[k];         \
            }                                                                        \
            _Pragma("unroll")                                                        \
            for (int k = 0; k < 4; ++k) {                                            \
                int idx = tid + k * 256;                                             \
                int drr = idx >> 3, g = idx & 7;                                     \
                unsigned u0 = (unsigned)__builtin_amdgcn_cvt_pk_fp8_f32(             \
                    (float)vreg[k][0], (float)vreg[k][1], 0, false);                 \
                u0 = (unsigned)__builtin_amdgcn_cvt_pk_fp8_f32(                      \
                    (float)vreg[k][2], (float)vreg[k][3], u0, true);                 \
                unsigned u1 = (unsigned)__builtin_amdgcn_cvt_pk_fp8_f32(             \
                    (float)vreg[k][4], (float)vreg[k][5], 0, false);                 \
                u1 = (unsigned)__builtin_amdgcn_cvt_pk_fp8_f32(                      \
                    (float)vreg[k][6], (float)vreg[k][7], u1, true);                 \
                *(uint2*)&Vt8[vsw][drr * 72 + ((g + (drr & 7)) & 7) * 8] =           \
                    make_uint2(u0, u1);                                              \
            }                                                                        \
        }                                                                            \
        if ((IT) + 2 < NITER) {                                                      \
            int jn = j0 + ((IT) + 2) * BN;                                           \
            _Pragma("unroll")                                                        \
            for (int k = 0; k < 4; ++k) {                                            \
                int idx = tid + k * 256;                                             \
                kreg[k] = *(const half8_t*)(q16 + (size_t)(jn + (idx >> 4)) * D      \
                                            + (idx & 15) * 8);                       \
                vreg[k] = *(const half8_t*)(qT16 + (size_t)(idx >> 3) * T + jn       \
                                            + (idx & 7) * 8);                        \
            }                                                                        \
        }                                                                            \
        floatx16 St[2];                                                              \
        _Pragma("unroll")                                                            \
        for (int jt = 0; jt < 2; ++jt) {                                             \
            const float* qb = &qqs[(IT) * 64 + jt * 32];                             \
            float4 b0 = *(const float4*)(qb + 8 * h);                                \
            float4 b1 = *(const float4*)(qb + 4 + 8 * h);                            \
            float4 b2 = *(const float4*)(qb + 16 + 8 * h);                           \
            float4 b3 = *(const float4*)(qb + 20 + 8 * h);                           \
            St[jt][0] = b0.x; St[jt][1] = b0.y; St[jt][2] = b0.z; St[jt][3] = b0.w;  \
            St[jt][4] = b1.x; St[jt][5] = b1.y; St[jt][6] = b1.z; St[jt][7] = b1.w;  \
            St[jt][8] = b2.x; St[jt][9] = b2.y; St[jt][10] = b2.z; St[jt][11] = b2.w;\
            St[jt][12] = b3.x; St[jt][13] = b3.y; St[jt][14] = b3.z; St[jt][15] = b3.w;\
            __builtin_amdgcn_s_setprio(1);                                           \
            _Pragma("unroll")                                                        \
            for (int ks = 0; ks < 8; ++ks) {                                         \
                half8_t a = *(const half8_t*)&Kt[cur][jt * 32 + sig][ks * 16 + h * 8];\
                St[jt] = __builtin_amdgcn_mfma_f32_32x32x16_f16(a, qfrag[ks],        \
                                                                St[jt], 0, 0, 0);    \
            }                                                                        \
            __builtin_amdgcn_s_setprio(0);                                           \
        }                                                                            \
        if ((IT) > 0) {                                                              \
            __builtin_amdgcn_s_setprio(1);                                           \
            _Pragma("unroll")                                                        \
            for (int jt = 0; jt < 2; ++jt)                                           \
                _Pragma("unroll")                                                    \
                for (int kb = 0; kb < 2; ++kb) {                                     \
                    long pb = PPR[jt * 2 + kb];                                      \
                    _Pragma("unroll")                                                \
                    for (int nt = 0; nt < 4; ++nt) {                                 \
                        int row = nt * 32 + l31;                                     \
                        int pg = ((jt * 4 + kb * 2 + h) + (row & 7)) & 7;            \
                        long va = *(const long*)&Vt8[vsr][row * 72 + pg * 8];        \
                        acc[nt] = __builtin_amdgcn_mfma_f32_32x32x16_fp8_fp8(        \
                            va, pb, acc[nt], 0, 0, 0);                               \
                    }                                                                \
                }                                                                    \
            __builtin_amdgcn_s_setprio(0);                                           \
        }                                                                            \
        float mx = St[0][0];                                                         \
        _Pragma("unroll")                                                            \
        for (int r = 1; r < 16; ++r) mx = fmaxf(mx, St[0][r]);                       \
        _Pragma("unroll")                                                            \
        for (int r = 0; r < 16; ++r) mx = fmaxf(mx, St[1][r]);                       \
        mx = fmaxf(mx, __shfl_xor(mx, 32));                                          \
        if (__any(mx > m_run)) {                                                     \
            float mnew = fmaxf(m_run, mx);                                           \
            float alpha = __builtin_amdgcn_exp2f(m_run - mnew);                      \
            _Pragma("unroll")                                                        \
            for (int nt = 0; nt < 4; ++nt)                                           \
                _Pragma("unroll")                                                    \
                for (int r = 0; r < 16; ++r) acc[nt][r] *= alpha;                    \
            l_run *= alpha;                                                          \
            m_run = mnew;                                                            \
        }                                                                            \
        float ps = 0.f;                                                              \
        _Pragma("unroll")                                                            \
        for (int jt = 0; jt < 2; ++jt)                                               \
            _Pragma("unroll")                                                        \
            for (int kb = 0; kb < 2; ++kb) {                                         \
                float p0 = __builtin_amdgcn_exp2f(St[jt][kb * 8 + 0] - m_run);       \
                float p1 = __builtin_amdgcn_exp2f(St[jt][kb * 8 + 1] - m_run);       \
                float p2 = __builtin_amdgcn_exp2f(St[jt][kb * 8 + 2] - m_run);       \
                float p3 = __builtin_amdgcn_exp2f(St[jt][kb * 8 + 3] - m_run);       \
                float p4 = __builtin_amdgcn_exp2f(St[jt][kb * 8 + 4] - m_run);       \
                float p5 = __builtin_amdgcn_exp2f(St[jt][kb * 8 + 5] - m_run);       \
                float p6 = __builtin_amdgcn_exp2f(St[jt][kb * 8 + 6] - m_run);       \
                float p7 = __builtin_amdgcn_exp2f(St[jt][kb * 8 + 7] - m_run);       \
                ps += ((p0 + p1) + (p2 + p3)) + ((p4 + p5) + (p6 + p7));             \
                unsigned a0 = (unsigned)__builtin_amdgcn_cvt_pk_fp8_f32(p0, p1, 0, false);\
                a0 = (unsigned)__builtin_amdgcn_cvt_pk_fp8_f32(p2, p3, a0, true);    \
                unsigned a1 = (unsigned)__builtin_amdgcn_cvt_pk_fp8_f32(p4, p5, 0, false);\
                a1 = (unsigned)__builtin_amdgcn_cvt_pk_fp8_f32(p6, p7, a1, true);    \
                PPW[jt * 2 + kb] = (long)(((unsigned long long)a1 << 32) | a0);      \
            }                                                                        \
        ps += __shfl_xor(ps, 32);                                                    \
        l_run += ps;                                                                 \
        __syncthreads();                                                             \
    } while (0)

    for (int it2 = 0; it2 < NITER; it2 += 2) {
        FBODY(it2, ppE, ppO);
        FBODY(it2 + 1, ppO, ppE);
    }
#undef FBODY

    // ---- epilogue: PV(NITER-1) with ppO, V slot (NITER-1)%3 = 0 ----
    __builtin_amdgcn_s_setprio(1);
#pragma unroll
    for (int jt = 0; jt < 2; ++jt)
#pragma unroll
        for (int kb = 0; kb < 2; ++kb) {
            long pb = ppO[jt * 2 + kb];
#pragma unroll
            for (int nt = 0; nt < 4; ++nt) {
                int row = nt * 32 + l31;
                int pg = ((jt * 4 + kb * 2 + h) + (row & 7)) & 7;
                long va = *(const long*)&Vt8[(NITER - 1) % 3][row * 72 + pg * 8];
                acc[nt] = __builtin_amdgcn_mfma_f32_32x32x16_fp8_fp8(va, pb, acc[nt], 0, 0, 0);
            }
        }
    __builtin_amdgcn_s_setprio(0);

    // ---- finalize: normalized O (O/l) as fp8 e4m3, 4B packed stores; m,l ----
    if (h == 0) {
        mpart[(size_t)sp * T + q] = m_run;
        lpart[(size_t)sp * T + q] = l_run;
    }
    float rinv = 1.0f / l_run;
#pragma unroll
    for (int nt = 0; nt < 4; ++nt)
#pragma unroll
        for (int rg = 0; rg < 4; ++rg) {
            float v0 = acc[nt][rg * 4 + 0] * rinv;
            float v1 = acc[nt][rg * 4 + 1] * rinv;
            float v2 = acc[nt][rg * 4 + 2] * rinv;
            float v3 = acc[nt][rg * 4 + 3] * rinv;
            unsigned u = (unsigned)__builtin_amdgcn_cvt_pk_fp8_f32(v0, v1, 0, false);
            u = (unsigned)__builtin_amdgcn_cvt_pk_fp8_f32(v2, v3, u, true);
            *(unsigned*)(Opart + ((size_t)sp * T + q) * D + nt * 32 + rg * 8 + 4 * h) = u;
        }
}

// ---------------------------------------------------------------------------
// combine: linv_i = 1/L_i from (m,l) partials, then h partial sums.
// grid 64, block 256   (R2 verbatim — best measured tail)
// ---------------------------------------------------------------------------
__global__ void combine_kernel(const float* __restrict__ x, const float* __restrict__ mpart,
                               const float* __restrict__ lpart, float* __restrict__ hpart) {
    __shared__ float linv_s[128];
    int b = blockIdx.x, t = threadIdx.x;
    if (t < 128) {
        int i = b * 128 + t;
        float mp[NSPLIT];
        float mstar = -INFINITY;
        for (int sp2 = 0; sp2 < NSPLIT; ++sp2) {
            mp[sp2] = mpart[(size_t)sp2 * T + i];
            mstar = fmaxf(mstar, mp[sp2]);
        }
        float L = 0.f;
        for (int sp2 = 0; sp2 < NSPLIT; ++sp2)
            L += __builtin_amdgcn_exp2f(mp[sp2] - mstar) * lpart[(size_t)sp2 * T + i];
        linv_s[t] = 1.0f / L;
    }
    __syncthreads();
    int d = t & 127, g = t >> 7;
    int r0 = g * 64;
    float s = 0.f;
    for (int r = 0; r < 64; ++r)
        s += x[(size_t)(b * 128 + r0 + r) * D + d] * linv_s[r0 + r];
    hpart[(size_t)(b * 2 + g) * 128 + d] = s;
}

// ---------------------------------------------------------------------------
// merge 8 fp8 split partials -> U_A (fp32); block 0 reduces hpart -> h.
// grid 512, block 256   (R2 verbatim)
// ---------------------------------------------------------------------------
__global__ void merge_kernel(const unsigned char* __restrict__ Opart, const float* __restrict__ mpart,
                             const float* __restrict__ lpart, float* __restrict__ U_A,
                             const float* __restrict__ hpart, float* __restrict__ h) {
    int t = threadIdx.x;
    if (blockIdx.x == 0 && t < 128) {
        float s = 0.f;
        for (int k = 0; k < 128; ++k) s += hpart[(size_t)k * 128 + t];
        h[t] = s;
    }
    int i = blockIdx.x * 16 + (t >> 4);
    int c = t & 15;
    float mp[NSPLIT];
    float mstar = -INFINITY;
    for (int sp = 0; sp < NSPLIT; ++sp) {
        mp[sp] = mpart[(size_t)sp * T + i];
        mstar = fmaxf(mstar, mp[sp]);
    }
    float L = 0.f;
    float u[8];
    for (int k = 0; k < 8; ++k) u[k] = 0.f;
    int d0 = c * 8;
    for (int sp = 0; sp < NSPLIT; ++sp) {
        float w = __builtin_amdgcn_exp2f(mp[sp] - mstar) * lpart[(size_t)sp * T + i];
        L += w;
        uint2 ow = *(const uint2*)(Opart + ((size_t)sp * T + i) * D + d0);
        u[0] += __builtin_amdgcn_cvt_f32_fp8(ow.x, 0) * w;
        u[1] += __builtin_amdgcn_cvt_f32_fp8(ow.x, 1) * w;
        u[2] += __builtin_amdgcn_cvt_f32_fp8(ow.x, 2) * w;
        u[3] += __builtin_amdgcn_cvt_f32_fp8(ow.x, 3) * w;
        u[4] += __builtin_amdgcn_cvt_f32_fp8(ow.y, 0) * w;
        u[5] += __builtin_amdgcn_cvt_f32_fp8(ow.y, 1) * w;
        u[6] += __builtin_amdgcn_cvt_f32_fp8(ow.y, 2) * w;
        u[7] += __builtin_amdgcn_cvt_f32_fp8(ow.y, 3) * w;
    }
    float invL = 1.0f / L;
    float4 s0 = make_float4(u[0] * invL, u[1] * invL, u[2] * invL, u[3] * invL);
    float4 s1 = make_float4(u[4] * invL, u[5] * invL, u[6] * invL, u[7] * invL);
    *(float4*)(U_A + (size_t)i * D + d0) = s0;
    *(float4*)(U_A + (size_t)i * D + d0 + 4) = s1;
}

// ---------------------------------------------------------------------------
// assemble G = [ctx, U_A, ctx*U_A, ctx*h]   grid 4096, block 256, float4/thread
// ---------------------------------------------------------------------------
__global__ void assemble_kernel(const float* __restrict__ x, const float* __restrict__ U_A,
                                const float* __restrict__ h, float* __restrict__ out) {
    const float* context = x;
    int gid = blockIdx.x * 256 + threadIdx.x;
    int base = gid * 4;
    int i = base >> 9;
    int c = base & 511;
    int seg = c >> 7, d = c & 127;
    float4 r;
    if (seg == 0) {
        r = *(const float4*)(context + (size_t)i * D + d);
    } else if (seg == 1) {
        r = *(const float4*)(U_A + (size_t)i * D + d);
    } else if (seg == 2) {
        float4 a = *(const float4*)(context + (size_t)i * D + d);
        float4 b = *(const float4*)(U_A + (size_t)i * D + d);
        r = make_float4(a.x * b.x, a.y * b.y, a.z * b.z, a.w * b.w);
    } else {
        float4 a = *(const float4*)(context + (size_t)i * D + d);
        float4 b = *(const float4*)(h + d);
        r = make_float4(a.x * b.x, a.y * b.y, a.z * b.z, a.w * b.w);
    }
    *(float4*)(out + base) = r;
}

// ---------------------------------------------------------------------------
extern "C" void kernel_launch(void* const* d_in, const int* in_sizes, int n_in,
                              void* d_out, int out_size, void* d_ws, size_t ws_size,
                              hipStream_t stream) {
    const float* x = (const float*)d_in[0];
    const float* kern = (const float*)d_in[1];
    float* out = (float*)d_out;

    char* w = (char*)d_ws;
    size_t off = 0;
    _Float16* q16  = (_Float16*)(w + off); off += (size_t)T * D * 2;   // 2 MB
    _Float16* qT16 = (_Float16*)(w + off); off += (size_t)T * D * 2;   // 2 MB
    _Float16* cm16 = (_Float16*)(w + off); off += (size_t)T * D * 2;   // 2 MB
    float* qq2   = (float*)(w + off); off += (size_t)T * 4;            // 32 KB
    float* mpart = (float*)(w + off); off += (size_t)NSPLIT * T * 4;   // 256 KB
    float* lpart = (float*)(w + off); off += (size_t)NSPLIT * T * 4;   // 256 KB
    float* U_A   = (float*)(w + off); off += (size_t)T * D * 4;        // 4 MB
    float* hpart = (float*)(w + off); off += (size_t)128 * 128 * 4;    // 64 KB
    float* h     = (float*)(w + off); off += (size_t)D * 4;

    // d_out doubles as fp8 split-partial scratch: 8 * T * D * 1B = 8 MB <= 16 MB
    unsigned char* Opart = (unsigned char*)d_out;

    prep_kernel<<<256, 256, 0, stream>>>(x, kern, q16, qT16, cm16, qq2);
    flash_kernel<<<512, 256, 0, stream>>>(q16, qT16, cm16, qq2, Opart, mpart, lpart);
    combine_kernel<<<64, 256, 0, stream>>>(x, mpart, lpart, hpart);
    merge_kernel<<<512, 256, 0, stream>>>(Opart, mpart, lpart, U_A, hpart, h);
    assemble_kernel<<<4096, 256, 0, stream>>>(x, U_A, h, out);
}

// Round 10
// 127.073 us; speedup vs baseline: 1.0544x; 1.0103x over previous
//
#include <hip/hip_runtime.h>
#include <hip/hip_bf16.h>

#define T 8192
#define D 128
#define NSPLIT 8
#define JLEN (T / NSPLIT)   /* 1024 */
#define BN 64
#define NITER (JLEN / BN)   /* 16 */
#define BM 128              /* rows per workgroup */
#define LOG2E 1.44269504088896f

typedef _Float16 half2_t __attribute__((ext_vector_type(2)));
typedef _Float16 half4_t __attribute__((ext_vector_type(4)));
typedef _Float16 half8_t __attribute__((ext_vector_type(8)));
typedef __fp16 fp16x2_t __attribute__((ext_vector_type(2)));
typedef float floatx4 __attribute__((ext_vector_type(4)));
typedef float floatx16 __attribute__((ext_vector_type(16)));

// ---------------------------------------------------------------------------
// prep: q16 = f16(question), qT16 = transpose, cm16 = f16(ctx*w_m*log2e),
// qq2[j] = (question[j].w_q)*log2e.  grid 256, block 256  (R2 verbatim)
// ---------------------------------------------------------------------------
__global__ void prep_kernel(const float* __restrict__ x, const float* __restrict__ kern,
                            _Float16* __restrict__ q16, _Float16* __restrict__ qT16,
                            _Float16* __restrict__ cm16, float* __restrict__ qq2) {
    const float* context  = x;
    const float* question = x + (size_t)T * D;
    const float* wq = kern + D;
    const float* wm = kern + 2 * D;
    __shared__ __align__(16) _Float16 tile[32][136];
    int j0 = blockIdx.x * 32;
    int t = threadIdx.x;
    int c4 = t & 31;
    int rsub = t >> 5;
    float4 wqv = ((const float4*)wq)[c4];
    float4 wmv = ((const float4*)wm)[c4];
    for (int p = 0; p < 4; ++p) {
        int row = p * 8 + rsub;
        float4 q = ((const float4*)(question + (size_t)(j0 + row) * D))[c4];
        float4 c = ((const float4*)(context  + (size_t)(j0 + row) * D))[c4];
        half4_t qh;
        qh[0] = (_Float16)q.x; qh[1] = (_Float16)q.y; qh[2] = (_Float16)q.z; qh[3] = (_Float16)q.w;
        *(half4_t*)(q16 + (size_t)(j0 + row) * D + c4 * 4) = qh;
        *(half4_t*)&tile[row][c4 * 4] = qh;
        half4_t ch;
        ch[0] = (_Float16)(c.x * wmv.x * LOG2E); ch[1] = (_Float16)(c.y * wmv.y * LOG2E);
        ch[2] = (_Float16)(c.z * wmv.z * LOG2E); ch[3] = (_Float16)(c.w * wmv.w * LOG2E);
        *(half4_t*)(cm16 + (size_t)(j0 + row) * D + c4 * 4) = ch;
        float s = q.x * wqv.x + q.y * wqv.y + q.z * wqv.z + q.w * wqv.w;
        for (int dx = 1; dx <= 16; dx <<= 1) s += __shfl_xor(s, dx);
        if (c4 == 0) qq2[j0 + row] = s * LOG2E;
    }
    __syncthreads();
    for (int p = 0; p < 2; ++p) {
        int chunk = t + p * 256;
        int d = chunk >> 2, jo = (chunk & 3) * 8;
        half8_t v;
        for (int s2 = 0; s2 < 8; ++s2) v[s2] = tile[jo + s2][d];
        *(half8_t*)(qT16 + (size_t)d * T + j0 + jo) = v;
    }
}

// ---------------------------------------------------------------------------
// flash — R2-exact structure (best per-dispatch: 55.2us) + tree reductions.
// EXACT rescale condition (mx > m_run): m_run MUST be the true running max
// because the h-path uses b[i] = max_j A[i,j] = 1/L_i, which holds only when
// the softmax shift is the true max.  R9's defer-max THR=8 broke this
// (absmax 112): deferral is U_A-safe (shift-invariant) but h-fatal.
// Structure log (do NOT revisit without new counter evidence):
//  R3 score-pipeline: spilled.  R4 4blk/CU: spilled.  R5 gload_lds: vmcnt
//  drain killed prefetch depth.  R6 3blk/CU small-tile: +5us.  R8 PV-shadow
//  +fp8V: +8us VALU.  R9 defer-max: WRONG (h-path).  Invariant: MFMA-busy
//  ~14us in every healthy build; latency-bound at 2 blk/CU, no pipe >31%.
// grid 512 = 64 row-blocks x 8 j-splits, block 256 (4 waves, 32 rows/wave)
// ---------------------------------------------------------------------------
__global__ __launch_bounds__(256, 2)
void flash_kernel(const _Float16* __restrict__ q16, const _Float16* __restrict__ qT16,
                  const _Float16* __restrict__ cm16, const float* __restrict__ qq2,
                  unsigned char* __restrict__ Opart, float* __restrict__ mpart,
                  float* __restrict__ lpart) {
    __shared__ __align__(16) _Float16 Kt[2][64][136];  // [key][d], stride 272B
    __shared__ __align__(16) _Float16 Vt[2][128][72];  // [d][rotated key granule]
    __shared__ __align__(16) float qqs[JLEN];          // biases for this split (4KB)

    const int bx = blockIdx.x;
    const int rb = bx >> 3;
    const int sp = bx & 7;
    const int tid = threadIdx.x;
    const int wave = tid >> 6;
    const int lane = tid & 63;
    const int l31 = lane & 31;
    const int h = lane >> 5;
    const int rbase = rb * BM + wave * 32;
    const int q = rbase + l31;                  // this lane's query row
    // sigma: swap bits 2<->3 (involution). Makes St C-regs == PV B-frags.
    const int sig = (l31 & 19) | ((l31 & 4) << 1) | ((l31 & 8) >> 1);

    ((float4*)qqs)[tid] = ((const float4*)(qq2 + (size_t)sp * JLEN))[tid];

    // B-operand of St: lane holds cm16[q][ks*16 + h*8 + 0..7]
    half8_t qfrag[8];
#pragma unroll
    for (int ks = 0; ks < 8; ++ks)
        qfrag[ks] = *(const half8_t*)(cm16 + (size_t)q * D + ks * 16 + h * 8);

    floatx16 acc[4];   // acc[nt]: O^T tile, row = d-within-tile, col = query
#pragma unroll
    for (int nt = 0; nt < 4; ++nt)
#pragma unroll
        for (int r = 0; r < 16; ++r) acc[nt][r] = 0.f;
    float m_run = -INFINITY, l_run = 0.f;

    const int j0 = sp * JLEN;
    half8_t kreg[4], vreg[4];
    // load tile 0 into regs, commit to buf0, prefetch tile 1
#pragma unroll
    for (int k = 0; k < 4; ++k) {
        int idx = tid + k * 256;
        kreg[k] = *(const half8_t*)(q16 + (size_t)(j0 + (idx >> 4)) * D + (idx & 15) * 8);
        vreg[k] = *(const half8_t*)(qT16 + (size_t)(idx >> 3) * T + j0 + (idx & 7) * 8);
    }
#pragma unroll
    for (int k = 0; k < 4; ++k) {
        int idx = tid + k * 256;
        *(half8_t*)&Kt[0][idx >> 4][(idx & 15) * 8] = kreg[k];
        int dr = idx >> 3, c8 = idx & 7;
        *(half8_t*)&Vt[0][dr][((c8 + (dr & 7)) & 7) * 8] = vreg[k];
    }
#pragma unroll
    for (int k = 0; k < 4; ++k) {
        int idx = tid + k * 256;
        kreg[k] = *(const half8_t*)(q16 + (size_t)(j0 + BN + (idx >> 4)) * D + (idx & 15) * 8);
        vreg[k] = *(const half8_t*)(qT16 + (size_t)(idx >> 3) * T + j0 + BN + (idx & 7) * 8);
    }
    __syncthreads();

    for (int it = 0; it < NITER; ++it) {
        const int cur = it & 1;
        // ---- commit tile it+1 into the other buffer ----
        if (it + 1 < NITER) {
#pragma unroll
            for (int k = 0; k < 4; ++k) {
                int idx = tid + k * 256;
                *(half8_t*)&Kt[cur ^ 1][idx >> 4][(idx & 15) * 8] = kreg[k];
                int dr = idx >> 3, c8 = idx & 7;
                *(half8_t*)&Vt[cur ^ 1][dr][((c8 + (dr & 7)) & 7) * 8] = vreg[k];
            }
        }
        // ---- issue tile it+2 global loads (latency overlaps compute) ----
        if (it + 2 < NITER) {
            int jn = j0 + (it + 2) * BN;
#pragma unroll
            for (int k = 0; k < 4; ++k) {
                int idx = tid + k * 256;
                kreg[k] = *(const half8_t*)(q16 + (size_t)(jn + (idx >> 4)) * D + (idx & 15) * 8);
                vreg[k] = *(const half8_t*)(qT16 + (size_t)(idx >> 3) * T + jn + (idx & 7) * 8);
            }
        }

        // ---- St = K Qm^T + bias (C-init); keys via sigma: key(reg r) =
        //      (r&3) + 4*((r>>2)&1) + 8h + 16*(r>>3)
        floatx16 St[2];
#pragma unroll
        for (int jt = 0; jt < 2; ++jt) {
            const float* qb = &qqs[it * 64 + jt * 32];
            float4 b0 = *(const float4*)(qb + 8 * h);
            float4 b1 = *(const float4*)(qb + 4 + 8 * h);
            float4 b2 = *(const float4*)(qb + 16 + 8 * h);
            float4 b3 = *(const float4*)(qb + 20 + 8 * h);
            St[jt][0]  = b0.x; St[jt][1]  = b0.y; St[jt][2]  = b0.z; St[jt][3]  = b0.w;
            St[jt][4]  = b1.x; St[jt][5]  = b1.y; St[jt][6]  = b1.z; St[jt][7]  = b1.w;
            St[jt][8]  = b2.x; St[jt][9]  = b2.y; St[jt][10] = b2.z; St[jt][11] = b2.w;
            St[jt][12] = b3.x; St[jt][13] = b3.y; St[jt][14] = b3.z; St[jt][15] = b3.w;
            __builtin_amdgcn_s_setprio(1);
#pragma unroll
            for (int ks = 0; ks < 8; ++ks) {
                half8_t a = *(const half8_t*)&Kt[cur][jt * 32 + sig][ks * 16 + h * 8];
                St[jt] = __builtin_amdgcn_mfma_f32_32x32x16_f16(a, qfrag[ks], St[jt], 0, 0, 0);
            }
            __builtin_amdgcn_s_setprio(0);
        }

        // ---- online softmax: tree max (depth 5), EXACT rescale ----
        float t8[8];
#pragma unroll
        for (int r = 0; r < 8; ++r)
            t8[r] = fmaxf(fmaxf(St[0][r], St[0][r + 8]), fmaxf(St[1][r], St[1][r + 8]));
        float mx = fmaxf(fmaxf(fmaxf(t8[0], t8[4]), fmaxf(t8[1], t8[5])),
                         fmaxf(fmaxf(t8[2], t8[6]), fmaxf(t8[3], t8[7])));
        mx = fmaxf(mx, __shfl_xor(mx, 32));
        if (__any(mx > m_run)) {   // EXACT: m_run must stay the true max (h-path)
            float mnew = fmaxf(m_run, mx);
            float alpha = __builtin_amdgcn_exp2f(m_run - mnew);
#pragma unroll
            for (int nt = 0; nt < 4; ++nt)
#pragma unroll
                for (int r = 0; r < 16; ++r) acc[nt][r] *= alpha;
            l_run *= alpha;
            m_run = mnew;
        }
        half2_t pp[2][8];
        float psa[4] = {0.f, 0.f, 0.f, 0.f};
#pragma unroll
        for (int jt = 0; jt < 2; ++jt)
#pragma unroll
            for (int r2 = 0; r2 < 8; ++r2) {
                float p0 = __builtin_amdgcn_exp2f(St[jt][2 * r2]     - m_run);
                float p1 = __builtin_amdgcn_exp2f(St[jt][2 * r2 + 1] - m_run);
                psa[r2 & 3] += p0 + p1;
                fp16x2_t pk = __builtin_amdgcn_cvt_pkrtz(p0, p1);
                pp[jt][r2] = __builtin_bit_cast(half2_t, pk);
            }
        float ps = (psa[0] + psa[1]) + (psa[2] + psa[3]);
        ps += __shfl_xor(ps, 32);
        l_run += ps;

        // ---- O^T += V^T P from Vt[cur]; B-frag = packed St regs (sigma) ----
        __builtin_amdgcn_s_setprio(1);
#pragma unroll
        for (int jt = 0; jt < 2; ++jt)
#pragma unroll
            for (int kb = 0; kb < 2; ++kb) {
                half8_t pb;
                pb[0] = pp[jt][kb * 4 + 0][0]; pb[1] = pp[jt][kb * 4 + 0][1];
                pb[2] = pp[jt][kb * 4 + 1][0]; pb[3] = pp[jt][kb * 4 + 1][1];
                pb[4] = pp[jt][kb * 4 + 2][0]; pb[5] = pp[jt][kb * 4 + 2][1];
                pb[6] = pp[jt][kb * 4 + 3][0]; pb[7] = pp[jt][kb * 4 + 3][1];
                const int pg = ((jt * 4 + kb * 2 + h) + (l31 & 7)) & 7;
#pragma unroll
                for (int nt = 0; nt < 4; ++nt) {
                    half8_t va = *(const half8_t*)&Vt[cur][nt * 32 + l31][pg * 8];
                    acc[nt] = __builtin_amdgcn_mfma_f32_32x32x16_f16(va, pb, acc[nt], 0, 0, 0);
                }
            }
        __builtin_amdgcn_s_setprio(0);
        __syncthreads();
    }

    // ---- finalize: normalized O (O/l) as fp8 e4m3, 4B packed stores; m,l ----
    if (h == 0) {
        mpart[(size_t)sp * T + q] = m_run;
        lpart[(size_t)sp * T + q] = l_run;
    }
    float rinv = 1.0f / l_run;
#pragma unroll
    for (int nt = 0; nt < 4; ++nt)
#pragma unroll
        for (int rg = 0; rg < 4; ++rg) {
            float v0 = acc[nt][rg * 4 + 0] * rinv;
            float v1 = acc[nt][rg * 4 + 1] * rinv;
            float v2 = acc[nt][rg * 4 + 2] * rinv;
            float v3 = acc[nt][rg * 4 + 3] * rinv;
            unsigned u = (unsigned)__builtin_amdgcn_cvt_pk_fp8_f32(v0, v1, 0, false);
            u = (unsigned)__builtin_amdgcn_cvt_pk_fp8_f32(v2, v3, u, true);
            *(unsigned*)(Opart + ((size_t)sp * T + q) * D + nt * 32 + rg * 8 + 4 * h) = u;
        }
}

// ---------------------------------------------------------------------------
// combine: linv_i = 1/L_i from (m,l) partials, then h partial sums.
// grid 64, block 256   (R2 verbatim — best measured tail)
// ---------------------------------------------------------------------------
__global__ void combine_kernel(const float* __restrict__ x, const float* __restrict__ mpart,
                               const float* __restrict__ lpart, float* __restrict__ hpart) {
    __shared__ float linv_s[128];
    int b = blockIdx.x, t = threadIdx.x;
    if (t < 128) {
        int i = b * 128 + t;
        float mp[NSPLIT];
        float mstar = -INFINITY;
        for (int sp2 = 0; sp2 < NSPLIT; ++sp2) {
            mp[sp2] = mpart[(size_t)sp2 * T + i];
            mstar = fmaxf(mstar, mp[sp2]);
        }
        float L = 0.f;
        for (int sp2 = 0; sp2 < NSPLIT; ++sp2)
            L += __builtin_amdgcn_exp2f(mp[sp2] - mstar) * lpart[(size_t)sp2 * T + i];
        linv_s[t] = 1.0f / L;
    }
    __syncthreads();
    int d = t & 127, g = t >> 7;
    int r0 = g * 64;
    float s = 0.f;
    for (int r = 0; r < 64; ++r)
        s += x[(size_t)(b * 128 + r0 + r) * D + d] * linv_s[r0 + r];
    hpart[(size_t)(b * 2 + g) * 128 + d] = s;
}

// ---------------------------------------------------------------------------
// merge 8 fp8 split partials -> U_A (fp32); block 0 reduces hpart -> h.
// grid 512, block 256   (R2 verbatim)
// ---------------------------------------------------------------------------
__global__ void merge_kernel(const unsigned char* __restrict__ Opart, const float* __restrict__ mpart,
                             const float* __restrict__ lpart, float* __restrict__ U_A,
                             const float* __restrict__ hpart, float* __restrict__ h) {
    int t = threadIdx.x;
    if (blockIdx.x == 0 && t < 128) {
        float s = 0.f;
        for (int k = 0; k < 128; ++k) s += hpart[(size_t)k * 128 + t];
        h[t] = s;
    }
    int i = blockIdx.x * 16 + (t >> 4);
    int c = t & 15;
    float mp[NSPLIT];
    float mstar = -INFINITY;
    for (int sp = 0; sp < NSPLIT; ++sp) {
        mp[sp] = mpart[(size_t)sp * T + i];
        mstar = fmaxf(mstar, mp[sp]);
    }
    float L = 0.f;
    float u[8];
    for (int k = 0; k < 8; ++k) u[k] = 0.f;
    int d0 = c * 8;
    for (int sp = 0; sp < NSPLIT; ++sp) {
        float w = __builtin_amdgcn_exp2f(mp[sp] - mstar) * lpart[(size_t)sp * T + i];
        L += w;
        uint2 ow = *(const uint2*)(Opart + ((size_t)sp * T + i) * D + d0);
        u[0] += __builtin_amdgcn_cvt_f32_fp8(ow.x, 0) * w;
        u[1] += __builtin_amdgcn_cvt_f32_fp8(ow.x, 1) * w;
        u[2] += __builtin_amdgcn_cvt_f32_fp8(ow.x, 2) * w;
        u[3] += __builtin_amdgcn_cvt_f32_fp8(ow.x, 3) * w;
        u[4] += __builtin_amdgcn_cvt_f32_fp8(ow.y, 0) * w;
        u[5] += __builtin_amdgcn_cvt_f32_fp8(ow.y, 1) * w;
        u[6] += __builtin_amdgcn_cvt_f32_fp8(ow.y, 2) * w;
        u[7] += __builtin_amdgcn_cvt_f32_fp8(ow.y, 3) * w;
    }
    float invL = 1.0f / L;
    float4 s0 = make_float4(u[0] * invL, u[1] * invL, u[2] * invL, u[3] * invL);
    float4 s1 = make_float4(u[4] * invL, u[5] * invL, u[6] * invL, u[7] * invL);
    *(float4*)(U_A + (size_t)i * D + d0) = s0;
    *(float4*)(U_A + (size_t)i * D + d0 + 4) = s1;
}

// ---------------------------------------------------------------------------
// assemble G = [ctx, U_A, ctx*U_A, ctx*h]   grid 4096, block 256, float4/thread
// ---------------------------------------------------------------------------
__global__ void assemble_kernel(const float* __restrict__ x, const float* __restrict__ U_A,
                                const float* __restrict__ h, float* __restrict__ out) {
    const float* context = x;
    int gid = blockIdx.x * 256 + threadIdx.x;
    int base = gid * 4;
    int i = base >> 9;
    int c = base & 511;
    int seg = c >> 7, d = c & 127;
    float4 r;
    if (seg == 0) {
        r = *(const float4*)(context + (size_t)i * D + d);
    } else if (seg == 1) {
        r = *(const float4*)(U_A + (size_t)i * D + d);
    } else if (seg == 2) {
        float4 a = *(const float4*)(context + (size_t)i * D + d);
        float4 b = *(const float4*)(U_A + (size_t)i * D + d);
        r = make_float4(a.x * b.x, a.y * b.y, a.z * b.z, a.w * b.w);
    } else {
        float4 a = *(const float4*)(context + (size_t)i * D + d);
        float4 b = *(const float4*)(h + d);
        r = make_float4(a.x * b.x, a.y * b.y, a.z * b.z, a.w * b.w);
    }
    *(float4*)(out + base) = r;
}

// ---------------------------------------------------------------------------
extern "C" void kernel_launch(void* const* d_in, const int* in_sizes, int n_in,
                              void* d_out, int out_size, void* d_ws, size_t ws_size,
                              hipStream_t stream) {
    const float* x = (const float*)d_in[0];
    const float* kern = (const float*)d_in[1];
    float* out = (float*)d_out;

    char* w = (char*)d_ws;
    size_t off = 0;
    _Float16* q16  = (_Float16*)(w + off); off += (size_t)T * D * 2;   // 2 MB
    _Float16* qT16 = (_Float16*)(w + off); off += (size_t)T * D * 2;   // 2 MB
    _Float16* cm16 = (_Float16*)(w + off); off += (size_t)T * D * 2;   // 2 MB
    float* qq2   = (float*)(w + off); off += (size_t)T * 4;            // 32 KB
    float* mpart = (float*)(w + off); off += (size_t)NSPLIT * T * 4;   // 256 KB
    float* lpart = (float*)(w + off); off += (size_t)NSPLIT * T * 4;   // 256 KB
    float* U_A   = (float*)(w + off); off += (size_t)T * D * 4;        // 4 MB
    float* hpart = (float*)(w + off); off += (size_t)128 * 128 * 4;    // 64 KB
    float* h     = (float*)(w + off); off += (size_t)D * 4;

    // d_out doubles as fp8 split-partial scratch: 8 * T * D * 1B = 8 MB <= 16 MB
    unsigned char* Opart = (unsigned char*)d_out;

    prep_kernel<<<256, 256, 0, stream>>>(x, kern, q16, qT16, cm16, qq2);
    flash_kernel<<<512, 256, 0, stream>>>(q16, qT16, cm16, qq2, Opart, mpart, lpart);
    combine_kernel<<<64, 256, 0, stream>>>(x, mpart, lpart, hpart);
    merge_kernel<<<512, 256, 0, stream>>>(Opart, mpart, lpart, U_A, hpart, h);
    assemble_kernel<<<4096, 256, 0, stream>>>(x, U_A, h, out);
}